// Round 11
// baseline (147.238 us; speedup 1.0000x reference)
//
#include <hip/hip_runtime.h>

using bf16x8   = __attribute__((ext_vector_type(8))) __bf16;
using f32x4    = __attribute__((ext_vector_type(4))) float;
using f32x16   = __attribute__((ext_vector_type(16))) float;
using floatv4  = __attribute__((ext_vector_type(4))) float;
using ushortv4 = __attribute__((ext_vector_type(4))) unsigned short;
using ushortv8 = __attribute__((ext_vector_type(8))) unsigned short;
using uintv2   = __attribute__((ext_vector_type(2))) unsigned int;
using uintv4   = __attribute__((ext_vector_type(4))) unsigned int;

#define N_SEQ 4096
#define N_B   4
#define DIMK  1024
#define HS    128
#define ROWS  (N_B * N_SEQ)
#define KVB   32
#define TT    (N_SEQ / KVB)   // 128 kv tiles
#define CEXPF 0.045084220027780106f   // log2(e)/32

__device__ __forceinline__ unsigned short f2bf(float f) {
    unsigned u = __builtin_bit_cast(unsigned, f);
    u += 0x7FFFu + ((u >> 16) & 1u);   // RNE
    return (unsigned short)(u >> 16);
}

__device__ __forceinline__ unsigned cvtpk(float lo, float hi) {
    unsigned r;
    asm("v_cvt_pk_bf16_f32 %0, %1, %2" : "=v"(r) : "v"(lo), "v"(hi));
    return r;
}

__device__ __forceinline__ void gload16(const unsigned short* g, unsigned short* l) {
    __builtin_amdgcn_global_load_lds(
        (const __attribute__((address_space(1))) unsigned int*)g,
        (__attribute__((address_space(3))) unsigned int*)l, 16, 0, 0);
}

// ---------------- cast W only: Wq, Wk, Wv -> bf16 (1.5 MB) [R7-proven] ----------------
__global__ __launch_bounds__(256) void castw_kernel(
    const float* __restrict__ Wq,
    const float* __restrict__ Wk,
    const float* __restrict__ Wv,
    unsigned short* __restrict__ Wb)
{
    const int blk = blockIdx.x;           // [0,192): 64 blocks per W
    const int z = blk >> 6;
    const float* src = (z == 0) ? Wq : (z == 1) ? Wk : Wv;
    unsigned short* dst = Wb + (size_t)z * (HS * DIMK);
    size_t i = (size_t)(blk & 63) * 2048 + (size_t)threadIdx.x * 8;
    floatv4 a = *reinterpret_cast<const floatv4*>(src + i);
    floatv4 b = *reinterpret_cast<const floatv4*>(src + i + 4);
    ushortv8 o = { f2bf(a.x), f2bf(a.y), f2bf(a.z), f2bf(a.w),
                   f2bf(b.x), f2bf(b.y), f2bf(b.z), f2bf(b.w) };
    *reinterpret_cast<ushortv8*>(dst + i) = o;
}

// ---------------- projection: O = X @ Wz^T, fused X cast, dbuf pipeline [R7-proven] ----------------
// grid (256, 3), block 256 = 4 waves. Tile 64 rows x 128 cols, BK=64.
// X: fp32 global -> regs -> cvt_pk -> swizzled ds_write (T14). W: bf16 gload_lds.
__global__ __launch_bounds__(256, 3) void proj_kernel(
    const float* __restrict__ X,
    const unsigned short* __restrict__ Wb,
    unsigned short* __restrict__ Qb,
    unsigned short* __restrict__ Kb,
    unsigned short* __restrict__ Vt)
{
    const int z = blockIdx.y;
    const unsigned short* __restrict__ Wz = Wb + (size_t)z * (HS * DIMK);
    const int row0 = blockIdx.x * 64;
    __shared__ unsigned short smem[2 * 64 * 64 + 2 * 128 * 64];   // Xs[2] | Ws[2]
    unsigned short* Xs0 = smem;
    unsigned short* Ws0 = smem + 2 * 64 * 64;
    const int tid = threadIdx.x;
    const int wv = tid >> 6, lane = tid & 63;
    const int lr = lane & 15, lg = lane >> 4;

    // X staging geometry: thread -> (row, 16-float chunk)
    const int xrow = tid >> 2, xc = (tid & 3) * 16;
    const float* xg = X + (size_t)(row0 + xrow) * DIMK + xc;
    const int xs0 = (tid & 3) * 2;          // first 8-short slot
    floatv4 xr[4];

    f32x4 acc[4][2] = {};

    auto loadX = [&](int k0) {
        #pragma unroll
        for (int i = 0; i < 4; ++i)
            xr[i] = *reinterpret_cast<const floatv4*>(xg + k0 + i * 4);
    };
    auto writeX = [&](int buf) {
        uintv4 w0 = { cvtpk(xr[0].x, xr[0].y), cvtpk(xr[0].z, xr[0].w),
                      cvtpk(xr[1].x, xr[1].y), cvtpk(xr[1].z, xr[1].w) };
        uintv4 w1 = { cvtpk(xr[2].x, xr[2].y), cvtpk(xr[2].z, xr[2].w),
                      cvtpk(xr[3].x, xr[3].y), cvtpk(xr[3].z, xr[3].w) };
        unsigned short* xb = Xs0 + buf * (64 * 64) + xrow * 64;
        *reinterpret_cast<uintv4*>(&xb[((xs0 ^ (xrow & 7)) * 8)]) = w0;
        *reinterpret_cast<uintv4*>(&xb[(((xs0 + 1) ^ (xrow & 7)) * 8)]) = w1;
    };
    auto stageW = [&](int buf, int k0) {
        #pragma unroll
        for (int i = 0; i < 4; ++i) {
            int g = wv * 4 + i;
            int r = g * 8 + (lane >> 3);
            int sp = (lane & 7) ^ (r & 7);
            gload16(Wz + (size_t)r * DIMK + k0 + sp * 8,
                    Ws0 + buf * (128 * 64) + g * 8 * 64);
        }
    };

    loadX(0);
    stageW(0, 0);
    asm volatile("s_waitcnt vmcnt(0)" ::: "memory");
    writeX(0);
    __syncthreads();

    for (int ks = 0; ks < DIMK / 64; ++ks) {
        const int cur = ks & 1;
        const bool more = (ks + 1 < DIMK / 64);
        if (more) { loadX((ks + 1) * 64); stageW(cur ^ 1, (ks + 1) * 64); }

        const unsigned short* Xc = Xs0 + cur * (64 * 64);
        const unsigned short* Wc = Ws0 + cur * (128 * 64);
        bf16x8 af[4][2], bfr[2][2];
        #pragma unroll
        for (int mi = 0; mi < 4; ++mi)
            #pragma unroll
            for (int kk = 0; kk < 2; ++kk)
                af[mi][kk] = *reinterpret_cast<const bf16x8*>(
                    &Xc[(mi * 16 + lr) * 64 + (((kk * 4 + lg) ^ (lr & 7)) * 8)]);
        #pragma unroll
        for (int ni = 0; ni < 2; ++ni)
            #pragma unroll
            for (int kk = 0; kk < 2; ++kk)
                bfr[ni][kk] = *reinterpret_cast<const bf16x8*>(
                    &Wc[(wv * 32 + ni * 16 + lr) * 64 + (((kk * 4 + lg) ^ (lr & 7)) * 8)]);
        #pragma unroll
        for (int kk = 0; kk < 2; ++kk)
            #pragma unroll
            for (int mi = 0; mi < 4; ++mi)
                #pragma unroll
                for (int ni = 0; ni < 2; ++ni)
                    acc[mi][ni] = __builtin_amdgcn_mfma_f32_16x16x32_bf16(
                        af[mi][kk], bfr[ni][kk], acc[mi][ni], 0, 0, 0);

        if (more) {
            asm volatile("s_waitcnt vmcnt(0)" ::: "memory");   // xr + W-LDS arrived
            writeX(cur ^ 1);
        }
        __syncthreads();
    }

    if (z < 2) {
        unsigned short* O = (z == 0) ? Qb : Kb;
        const float qs = (z == 0) ? CEXPF : 1.0f;  // Q pre-scaled by log2(e)/32
        #pragma unroll
        for (int mi = 0; mi < 4; ++mi) {
            int rowb = row0 + mi * 16 + lg * 4;
            #pragma unroll
            for (int ni = 0; ni < 2; ++ni) {
                int col = wv * 32 + ni * 16 + lr;
                #pragma unroll
                for (int r = 0; r < 4; ++r)
                    O[(size_t)(rowb + r) * HS + col] = f2bf(acc[mi][ni][r] * qs);
            }
        }
    } else {
        unsigned short* Cs = smem;      // [64][136]
        #pragma unroll
        for (int mi = 0; mi < 4; ++mi)
            #pragma unroll
            for (int ni = 0; ni < 2; ++ni)
                #pragma unroll
                for (int r = 0; r < 4; ++r)
                    Cs[(mi * 16 + lg * 4 + r) * 136 + wv * 32 + ni * 16 + lr] = f2bf(acc[mi][ni][r]);
        __syncthreads();
        const int b  = row0 >> 12;
        const int n0 = row0 & (N_SEQ - 1);
        #pragma unroll
        for (int i = 0; i < 2; ++i) {
            int idx = tid + i * 256;          // [0,512): 64 n-chunks x 128 d? -> 128 d x 4 chunks
            int d = idx >> 2, c8 = idx & 3;
            ushortv8 v;
            #pragma unroll
            for (int j = 0; j < 8; ++j)
                v[j] = Cs[((c8 * 2 + 0) * 8 + j) * 136 + d];
            *reinterpret_cast<ushortv8*>(Vt + (size_t)b * HS * N_SEQ + (size_t)d * N_SEQ + n0 + c8 * 16) = v;
            ushortv8 v2;
            #pragma unroll
            for (int j = 0; j < 8; ++j)
                v2[j] = Cs[((c8 * 2 + 1) * 8 + j) * 136 + d];
            *reinterpret_cast<ushortv8*>(Vt + (size_t)b * HS * N_SEQ + (size_t)d * N_SEQ + n0 + c8 * 16 + 8) = v2;
        }
    }
}

// ---------------- flash attention: K 3-buf + V 2-buf (40 KB), 4 blocks/CU, counted vmcnt ----------------
// grid (128, S), block 256 = 4 waves, 32 q-rows/wave.
__global__ __launch_bounds__(256, 4) void attn_kernel(
    const unsigned short* __restrict__ Qb,
    const unsigned short* __restrict__ Kb,
    const unsigned short* __restrict__ Vt,
    unsigned short* __restrict__ part,   // [512][S][32][128] bf16
    float* __restrict__ plsum,           // [512][S][32]
    int S)
{
    const int qblk  = blockIdx.x;      // [0,128)
    const int split = blockIdx.y;      // [0,S)
    const int tid = threadIdx.x;
    const int wv = tid >> 6, lane = tid & 63;
    const int l31 = lane & 31, h = lane >> 5;
    const int b    = qblk >> 5;
    const int row0 = (qblk & 31) * 128 + wv * 32;

    __shared__ unsigned short Ks[3][KVB * 128];   // 24 KB: [kv][hd], slot16 ^= (kv&7)
    __shared__ unsigned short Vs[2][128 * KVB];   // 16 KB: [d][kv],  slot4  ^= ((d>>1)&3)

    // Q as B-fragment (pre-scaled by log2(e)/32 in proj)
    bf16x8 qf[8];
    {
        const unsigned short* qp = Qb + ((size_t)b * N_SEQ + row0 + l31) * HS + h * 8;
        #pragma unroll
        for (int kk = 0; kk < 8; ++kk)
            qf[kk] = *reinterpret_cast<const bf16x8*>(qp + kk * 16);
    }

    const int base = TT / S, rem = TT % S;
    const int nt = base + (split < rem ? 1 : 0);
    const int kv_begin = (split * base + (split < rem ? split : rem)) * KVB;

    const unsigned short* Kbb = Kb + (size_t)b * N_SEQ * HS;
    const unsigned short* Vbb = Vt + (size_t)b * HS * N_SEQ;

    auto stageK = [&](int buf, int kv0) {
        #pragma unroll
        for (int i = 0; i < 2; ++i) {          // K [32][128]
            int g = wv * 2 + i;
            int r = g * 4 + (lane >> 4);
            int sp = (lane & 15) ^ (r & 7);
            gload16(Kbb + (size_t)(kv0 + r) * HS + sp * 8, &Ks[buf][g * 4 * 128]);
        }
    };
    auto stageV = [&](int buf, int kv0) {
        #pragma unroll
        for (int i = 0; i < 2; ++i) {          // V^T [128][32]
            int g = wv * 2 + i;
            int r = g * 16 + (lane >> 2);
            int sp = (lane & 3) ^ ((r >> 1) & 3);
            gload16(Vbb + (size_t)r * N_SEQ + kv0 + sp * 8, &Vs[buf][g * 16 * KVB]);
        }
    };

    f32x16 ctx[4] = {};
    float lsum = 0.f;

    // prologue: K(0), V(0), K(1) -> 6 loads/wave in flight
    stageK(0, kv_begin);
    stageV(0, kv_begin);
    if (nt > 1) stageK(1, kv_begin + KVB);

    int kcur = 0, vcur = 0;
    for (int t = 0; t < nt; ++t) {
        // top wait: K(t),V(t) are the oldest 4 of <=6 outstanding; K(t+1) may stay in flight
        if (t + 1 < nt)
            asm volatile("s_waitcnt vmcnt(2)\n\ts_barrier" ::: "memory");
        else
            asm volatile("s_waitcnt vmcnt(0)\n\ts_barrier" ::: "memory");

        // issue next stages (V one-ahead into other V-buf; K two-ahead into third K-buf)
        if (t + 1 < nt) stageV(vcur ^ 1, kv_begin + (t + 1) * KVB);
        if (t + 2 < nt) {
            int knxt = kcur + 2; if (knxt >= 3) knxt -= 3;
            stageK(knxt, kv_begin + (t + 2) * KVB);
        }

        // S^T = K Q^T (swapped), two independent accumulator chains
        f32x16 st0 = {}, st1 = {};
        __builtin_amdgcn_s_setprio(1);
        #pragma unroll
        for (int kk = 0; kk < 8; kk += 2) {
            bf16x8 kf0 = *reinterpret_cast<const bf16x8*>(
                &Ks[kcur][l31 * 128 + (((kk * 2 + h) ^ (l31 & 7)) * 8)]);
            st0 = __builtin_amdgcn_mfma_f32_32x32x16_bf16(kf0, qf[kk], st0, 0, 0, 0);
            bf16x8 kf1 = *reinterpret_cast<const bf16x8*>(
                &Ks[kcur][l31 * 128 + ((((kk + 1) * 2 + h) ^ (l31 & 7)) * 8)]);
            st1 = __builtin_amdgcn_mfma_f32_32x32x16_bf16(kf1, qf[kk + 1], st1, 0, 0, 0);
        }
        __builtin_amdgcn_s_setprio(0);

        // P = exp2(st0+st1) in registers (Q pre-scaled)
        float p[16];
        #pragma unroll
        for (int r = 0; r < 16; ++r)
            p[r] = __builtin_amdgcn_exp2f(st0[r] + st1[r]);

        // lsum: per-lane row-sum tree (q = l31 is lane-local)
        {
            float a0 = (p[0] + p[1])   + (p[2] + p[3]);
            float a1 = (p[4] + p[5])   + (p[6] + p[7]);
            float a2 = (p[8] + p[9])   + (p[10] + p[11]);
            float a3 = (p[12] + p[13]) + (p[14] + p[15]);
            lsum += (a0 + a1) + (a2 + a3);
        }

        // repack to PV A-fragments via cvt_pk + permlane32_swap
        bf16x8 pf[2];
        #pragma unroll
        for (int half = 0; half < 2; ++half) {
            unsigned a  = cvtpk(p[half*8 + 0], p[half*8 + 1]);
            unsigned bq = cvtpk(p[half*8 + 2], p[half*8 + 3]);
            unsigned c  = cvtpk(p[half*8 + 4], p[half*8 + 5]);
            unsigned d  = cvtpk(p[half*8 + 6], p[half*8 + 7]);
            asm("v_permlane32_swap_b32 %0, %1" : "+v"(a), "+v"(c));
            asm("v_permlane32_swap_b32 %0, %1" : "+v"(bq), "+v"(d));
            uintv4 w = { a, bq, c, d };
            pf[half] = __builtin_bit_cast(bf16x8, w);
        }

        __builtin_amdgcn_s_setprio(1);
        #pragma unroll
        for (int dt = 0; dt < 4; ++dt) {
            int d = dt * 32 + l31;
            bf16x8 vf0 = *reinterpret_cast<const bf16x8*>(
                &Vs[vcur][d * KVB + (((0 + h) ^ ((d >> 1) & 3)) * 8)]);
            ctx[dt] = __builtin_amdgcn_mfma_f32_32x32x16_bf16(pf[0], vf0, ctx[dt], 0, 0, 0);
            bf16x8 vf1 = *reinterpret_cast<const bf16x8*>(
                &Vs[vcur][d * KVB + (((2 + h) ^ ((d >> 1) & 3)) * 8)]);
            ctx[dt] = __builtin_amdgcn_mfma_f32_32x32x16_bf16(pf[1], vf1, ctx[dt], 0, 0, 0);
        }
        __builtin_amdgcn_s_setprio(0);

        kcur = (kcur == 2) ? 0 : kcur + 1;
        vcur ^= 1;
    }

    lsum += __shfl_xor(lsum, 32);

    const int qt = qblk * 4 + wv;              // [0,512) 32-row tile
    unsigned short* pp = part + ((size_t)qt * S + split) * (32 * 128);
    #pragma unroll
    for (int rp = 0; rp < 4; ++rp)
        #pragma unroll
        for (int rq = 0; rq < 4; ++rq) {
            const int r = rp * 4 + rq;
            const int q = rq + 8 * rp + 4 * h;
            #pragma unroll
            for (int dt = 0; dt < 4; ++dt)
                pp[q * 128 + dt * 32 + l31] = (unsigned short)(cvtpk(ctx[dt][r], ctx[dt][r]) & 0xFFFFu);
        }
    if (h == 0)
        plsum[((size_t)qt * S + split) * 32 + l31] = lsum;
}

// combine KV-split partials: out = (sum_s part_s) / (sum_s lsum_s)
__global__ __launch_bounds__(256) void reduce_kernel(
    const unsigned short* __restrict__ part,
    const float* __restrict__ plsum,
    float* __restrict__ out, int S)
{
    const int id = blockIdx.x * 256 + threadIdx.x;   // [0, 16384*128/4)
    const int d4 = (id & 31) * 4;
    const int grow = id >> 5;                        // global q row
    const int qt = grow >> 5, q = grow & 31;
    f32x4 c = {0.f, 0.f, 0.f, 0.f};
    float l = 0.f;
    for (int s = 0; s < S; ++s) {
        ushortv4 pv = *reinterpret_cast<const ushortv4*>(
            &part[(((size_t)qt * S + s) * 32 + q) * 128 + d4]);
        #pragma unroll
        for (int j = 0; j < 4; ++j)
            c[j] += __builtin_bit_cast(float, (unsigned)pv[j] << 16);
        l += plsum[((size_t)qt * S + s) * 32 + q];
    }
    float inv = 1.0f / l;
    f32x4 o = { c[0]*inv, c[1]*inv, c[2]*inv, c[3]*inv };
    *reinterpret_cast<f32x4*>(&out[(size_t)grow * 128 + d4]) = o;
}

extern "C" void kernel_launch(void* const* d_in, const int* in_sizes, int n_in,
                              void* d_out, int out_size, void* d_ws, size_t ws_size,
                              hipStream_t stream) {
    const float* x  = (const float*)d_in[0];
    const float* wq = (const float*)d_in[1];
    const float* wk = (const float*)d_in[2];
    const float* wv = (const float*)d_in[3];

    // ws layout: Wb | Qb | Kb | Vt | plsum(max S) | part
    unsigned short* Wb = (unsigned short*)d_ws;                 // 0.79 MB
    unsigned short* Qb = Wb + (size_t)3 * HS * DIMK;
    unsigned short* Kb = Qb + (size_t)ROWS * HS;
    unsigned short* Vt = Kb + (size_t)ROWS * HS;
    float* plsum = (float*)(Vt + (size_t)N_B * HS * N_SEQ);

    const size_t fixed = (size_t)3 * HS * DIMK * 2 + (size_t)3 * ROWS * HS * 2;  // 13.4 MB
    const size_t per_split = (size_t)512 * 32 * 4 + (size_t)512 * 32 * 128 * 2;  // 4.26 MB

    int S;
    if      (ws_size >= fixed + 8 * per_split) S = 8;   // grid 1024 = 4 blocks/CU exact
    else if (ws_size >= fixed + 6 * per_split) S = 6;
    else if (ws_size >= fixed + 4 * per_split) S = 4;
    else if (ws_size >= fixed + 2 * per_split) S = 2;
    else                                       S = 1;

    unsigned short* part = (unsigned short*)(plsum + (size_t)512 * S * 32);

    castw_kernel<<<192, 256, 0, stream>>>(wq, wk, wv, Wb);
    proj_kernel<<<dim3(256, 3), 256, 0, stream>>>(x, Wb, Qb, Kb, Vt);
    attn_kernel<<<dim3(128, S), 256, 0, stream>>>(Qb, Kb, Vt, part, plsum, S);
    reduce_kernel<<<(ROWS * HS) / 1024, 256, 0, stream>>>(part, plsum, (float*)d_out, S);
}

// Round 12
// 83.217 us; speedup vs baseline: 1.7693x; 1.7693x over previous
//
#include <hip/hip_runtime.h>

using bf16x8   = __attribute__((ext_vector_type(8))) __bf16;
using f32x4    = __attribute__((ext_vector_type(4))) float;
using f32x16   = __attribute__((ext_vector_type(16))) float;
using floatv4  = __attribute__((ext_vector_type(4))) float;
using ushortv4 = __attribute__((ext_vector_type(4))) unsigned short;
using ushortv8 = __attribute__((ext_vector_type(8))) unsigned short;
using uintv4   = __attribute__((ext_vector_type(4))) unsigned int;

#define N_SEQ 4096
#define N_B   4
#define DIMK  1024
#define HS    128
#define ROWS  (N_B * N_SEQ)
#define KVB   32
#define TT    (N_SEQ / KVB)   // 128 kv tiles
#define CEXPF 0.045084220027780106f   // log2(e)/32

__device__ __forceinline__ unsigned short f2bf(float f) {
    unsigned u = __builtin_bit_cast(unsigned, f);
    u += 0x7FFFu + ((u >> 16) & 1u);   // RNE
    return (unsigned short)(u >> 16);
}

__device__ __forceinline__ unsigned cvtpk(float lo, float hi) {
    unsigned r;
    asm("v_cvt_pk_bf16_f32 %0, %1, %2" : "=v"(r) : "v"(lo), "v"(hi));
    return r;
}

__device__ __forceinline__ void gload16(const unsigned short* g, unsigned short* l) {
    __builtin_amdgcn_global_load_lds(
        (const __attribute__((address_space(1))) unsigned int*)g,
        (__attribute__((address_space(3))) unsigned int*)l, 16, 0, 0);
}

// ---------------- cast W only: Wq, Wk, Wv -> bf16 (1.5 MB) ----------------
__global__ __launch_bounds__(256) void castw_kernel(
    const float* __restrict__ Wq,
    const float* __restrict__ Wk,
    const float* __restrict__ Wv,
    unsigned short* __restrict__ Wb)
{
    const int blk = blockIdx.x;           // [0,192): 64 blocks per W
    const int z = blk >> 6;
    const float* src = (z == 0) ? Wq : (z == 1) ? Wk : Wv;
    unsigned short* dst = Wb + (size_t)z * (HS * DIMK);
    size_t i = (size_t)(blk & 63) * 2048 + (size_t)threadIdx.x * 8;
    floatv4 a = *reinterpret_cast<const floatv4*>(src + i);
    floatv4 b = *reinterpret_cast<const floatv4*>(src + i + 4);
    ushortv8 o = { f2bf(a.x), f2bf(a.y), f2bf(a.z), f2bf(a.w),
                   f2bf(b.x), f2bf(b.y), f2bf(b.z), f2bf(b.w) };
    *reinterpret_cast<ushortv8*>(dst + i) = o;
}

// ---------------- projection: O = X @ Wz^T, fused X cast, dbuf pipeline [R7-proven] ----------------
// grid (256, 3), block 256 = 4 waves. Tile 64 rows x 128 cols, BK=64.
__global__ __launch_bounds__(256, 3) void proj_kernel(
    const float* __restrict__ X,
    const unsigned short* __restrict__ Wb,
    unsigned short* __restrict__ Qb,
    unsigned short* __restrict__ Kb,
    unsigned short* __restrict__ Vt)
{
    const int z = blockIdx.y;
    const unsigned short* __restrict__ Wz = Wb + (size_t)z * (HS * DIMK);
    const int row0 = blockIdx.x * 64;
    __shared__ unsigned short smem[2 * 64 * 64 + 2 * 128 * 64];   // Xs[2] | Ws[2]
    unsigned short* Xs0 = smem;
    unsigned short* Ws0 = smem + 2 * 64 * 64;
    const int tid = threadIdx.x;
    const int wv = tid >> 6, lane = tid & 63;
    const int lr = lane & 15, lg = lane >> 4;

    // X staging geometry: thread -> (row, 16-float chunk)
    const int xrow = tid >> 2, xc = (tid & 3) * 16;
    const float* xg = X + (size_t)(row0 + xrow) * DIMK + xc;
    const int xs0 = (tid & 3) * 2;          // first 8-short slot
    floatv4 xr[4];

    f32x4 acc[4][2] = {};

    auto loadX = [&](int k0) {
        #pragma unroll
        for (int i = 0; i < 4; ++i)
            xr[i] = *reinterpret_cast<const floatv4*>(xg + k0 + i * 4);
    };
    auto writeX = [&](int buf) {
        uintv4 w0 = { cvtpk(xr[0].x, xr[0].y), cvtpk(xr[0].z, xr[0].w),
                      cvtpk(xr[1].x, xr[1].y), cvtpk(xr[1].z, xr[1].w) };
        uintv4 w1 = { cvtpk(xr[2].x, xr[2].y), cvtpk(xr[2].z, xr[2].w),
                      cvtpk(xr[3].x, xr[3].y), cvtpk(xr[3].z, xr[3].w) };
        unsigned short* xb = Xs0 + buf * (64 * 64) + xrow * 64;
        *reinterpret_cast<uintv4*>(&xb[((xs0 ^ (xrow & 7)) * 8)]) = w0;
        *reinterpret_cast<uintv4*>(&xb[(((xs0 + 1) ^ (xrow & 7)) * 8)]) = w1;
    };
    auto stageW = [&](int buf, int k0) {
        #pragma unroll
        for (int i = 0; i < 4; ++i) {
            int g = wv * 4 + i;
            int r = g * 8 + (lane >> 3);
            int sp = (lane & 7) ^ (r & 7);
            gload16(Wz + (size_t)r * DIMK + k0 + sp * 8,
                    Ws0 + buf * (128 * 64) + g * 8 * 64);
        }
    };

    loadX(0);
    stageW(0, 0);
    asm volatile("s_waitcnt vmcnt(0)" ::: "memory");
    writeX(0);
    __syncthreads();

    for (int ks = 0; ks < DIMK / 64; ++ks) {
        const int cur = ks & 1;
        const bool more = (ks + 1 < DIMK / 64);
        if (more) { loadX((ks + 1) * 64); stageW(cur ^ 1, (ks + 1) * 64); }

        const unsigned short* Xc = Xs0 + cur * (64 * 64);
        const unsigned short* Wc = Ws0 + cur * (128 * 64);
        bf16x8 af[4][2], bfr[2][2];
        #pragma unroll
        for (int mi = 0; mi < 4; ++mi)
            #pragma unroll
            for (int kk = 0; kk < 2; ++kk)
                af[mi][kk] = *reinterpret_cast<const bf16x8*>(
                    &Xc[(mi * 16 + lr) * 64 + (((kk * 4 + lg) ^ (lr & 7)) * 8)]);
        #pragma unroll
        for (int ni = 0; ni < 2; ++ni)
            #pragma unroll
            for (int kk = 0; kk < 2; ++kk)
                bfr[ni][kk] = *reinterpret_cast<const bf16x8*>(
                    &Wc[(wv * 32 + ni * 16 + lr) * 64 + (((kk * 4 + lg) ^ (lr & 7)) * 8)]);
        #pragma unroll
        for (int kk = 0; kk < 2; ++kk)
            #pragma unroll
            for (int mi = 0; mi < 4; ++mi)
                #pragma unroll
                for (int ni = 0; ni < 2; ++ni)
                    acc[mi][ni] = __builtin_amdgcn_mfma_f32_16x16x32_bf16(
                        af[mi][kk], bfr[ni][kk], acc[mi][ni], 0, 0, 0);

        if (more) {
            asm volatile("s_waitcnt vmcnt(0)" ::: "memory");   // xr + W-LDS arrived
            writeX(cur ^ 1);
        }
        __syncthreads();
    }

    if (z < 2) {
        unsigned short* O = (z == 0) ? Qb : Kb;
        const float qs = (z == 0) ? CEXPF : 1.0f;  // Q pre-scaled by log2(e)/32
        #pragma unroll
        for (int mi = 0; mi < 4; ++mi) {
            int rowb = row0 + mi * 16 + lg * 4;
            #pragma unroll
            for (int ni = 0; ni < 2; ++ni) {
                int col = wv * 32 + ni * 16 + lr;
                #pragma unroll
                for (int r = 0; r < 4; ++r)
                    O[(size_t)(rowb + r) * HS + col] = f2bf(acc[mi][ni][r] * qs);
            }
        }
    } else {
        unsigned short* Cs = smem;      // [64][136]
        #pragma unroll
        for (int mi = 0; mi < 4; ++mi)
            #pragma unroll
            for (int ni = 0; ni < 2; ++ni)
                #pragma unroll
                for (int r = 0; r < 4; ++r)
                    Cs[(mi * 16 + lg * 4 + r) * 136 + wv * 32 + ni * 16 + lr] = f2bf(acc[mi][ni][r]);
        __syncthreads();
        const int b  = row0 >> 12;
        const int n0 = row0 & (N_SEQ - 1);
        #pragma unroll
        for (int i = 0; i < 2; ++i) {
            int idx = tid + i * 256;
            int d = idx >> 2, c8 = idx & 3;
            ushortv8 v;
            #pragma unroll
            for (int j = 0; j < 8; ++j)
                v[j] = Cs[(c8 * 8 + j) * 136 + d];
            *reinterpret_cast<ushortv8*>(Vt + (size_t)b * HS * N_SEQ + (size_t)d * N_SEQ + n0 + c8 * 8) = v;
        }
        #pragma unroll
        for (int i = 0; i < 2; ++i) {
            int idx = tid + i * 256;
            int d = idx >> 2, c8 = (idx & 3) + 4;
            ushortv8 v;
            #pragma unroll
            for (int j = 0; j < 8; ++j)
                v[j] = Cs[(c8 * 8 + j) * 136 + d];
            *reinterpret_cast<ushortv8*>(Vt + (size_t)b * HS * N_SEQ + (size_t)d * N_SEQ + n0 + c8 * 8) = v;
        }
    }
}

// ---------------- flash attention: R7-exact + XCD-aware block swizzle ----------------
// flat grid 128*S, block 256 = 4 waves, 32 q-rows/wave. LDS = 3x(K 8KB + V 8KB) = 48 KB.
// S==6: bid = chunk*256 + member*8 + xcd; group g=chunk*8+xcd -> (b,split); all 32
// members of a (b,split) K/V segment land on one XCD (round-robin bid%8 mapping).
__global__ __launch_bounds__(256, 3) void attn_kernel(
    const unsigned short* __restrict__ Qb,
    const unsigned short* __restrict__ Kb,
    const unsigned short* __restrict__ Vt,
    unsigned short* __restrict__ part,   // [512][S][32][128] bf16
    float* __restrict__ plsum,           // [512][S][32]
    int S)
{
    int qblk, split;
    {
        const int bid = blockIdx.x;
        if (S == 6) {
            const int chunk = bid >> 8, rem = bid & 255;
            const int member = rem >> 3, xcd = rem & 7;
            const int g = chunk * 8 + xcd;       // [0,24)
            const int b = g / 6;
            split = g - b * 6;
            qblk = b * 32 + member;
        } else {
            qblk = bid & 127;
            split = bid >> 7;
        }
    }
    const int tid = threadIdx.x;
    const int wv = tid >> 6, lane = tid & 63;
    const int l31 = lane & 31, h = lane >> 5;
    const int b    = qblk >> 5;
    const int row0 = (qblk & 31) * 128 + wv * 32;

    __shared__ unsigned short Ks[3][KVB * 128];   // [kv][hd], slot16 ^= (kv&7)
    __shared__ unsigned short Vs[3][128 * KVB];   // [d][kv],  slot4  ^= ((d>>1)&3)

    // Q as B-fragment (pre-scaled by log2(e)/32 in proj)
    bf16x8 qf[8];
    {
        const unsigned short* qp = Qb + ((size_t)b * N_SEQ + row0 + l31) * HS + h * 8;
        #pragma unroll
        for (int kk = 0; kk < 8; ++kk)
            qf[kk] = *reinterpret_cast<const bf16x8*>(qp + kk * 16);
    }

    const int base = TT / S, rem = TT % S;
    const int nt = base + (split < rem ? 1 : 0);
    const int kv_begin = (split * base + (split < rem ? split : rem)) * KVB;

    const unsigned short* Kbb = Kb + (size_t)b * N_SEQ * HS;
    const unsigned short* Vbb = Vt + (size_t)b * HS * N_SEQ;

    auto stage = [&](int buf, int kv0) {
        #pragma unroll
        for (int i = 0; i < 2; ++i) {          // K [32][128]
            int g = wv * 2 + i;
            int r = g * 4 + (lane >> 4);
            int sp = (lane & 15) ^ (r & 7);
            gload16(Kbb + (size_t)(kv0 + r) * HS + sp * 8, &Ks[buf][g * 4 * 128]);
        }
        #pragma unroll
        for (int i = 0; i < 2; ++i) {          // V^T [128][32]
            int g = wv * 2 + i;
            int r = g * 16 + (lane >> 2);
            int sp = (lane & 3) ^ ((r >> 1) & 3);
            gload16(Vbb + (size_t)r * N_SEQ + kv0 + sp * 8, &Vs[buf][g * 16 * KVB]);
        }
    };

    f32x16 ctx[4] = {};
    float lsum = 0.f;

    stage(0, kv_begin);
    stage(1, kv_begin + KVB);
    int cur = 0, nxt = 2;
    for (int t = 0; t < nt; ++t) {
        if (t + 2 < nt) {
            asm volatile("s_waitcnt vmcnt(4)\n\ts_barrier" ::: "memory");
            stage(nxt, kv_begin + (t + 2) * KVB);
        } else if (t + 1 < nt) {
            asm volatile("s_waitcnt vmcnt(4)\n\ts_barrier" ::: "memory");
        } else {
            asm volatile("s_waitcnt vmcnt(0)\n\ts_barrier" ::: "memory");
        }

        // S^T = K Q^T (swapped), two independent accumulator chains
        f32x16 st0 = {}, st1 = {};
        __builtin_amdgcn_s_setprio(1);
        #pragma unroll
        for (int kk = 0; kk < 8; kk += 2) {
            bf16x8 kf0 = *reinterpret_cast<const bf16x8*>(
                &Ks[cur][l31 * 128 + (((kk * 2 + h) ^ (l31 & 7)) * 8)]);
            st0 = __builtin_amdgcn_mfma_f32_32x32x16_bf16(kf0, qf[kk], st0, 0, 0, 0);
            bf16x8 kf1 = *reinterpret_cast<const bf16x8*>(
                &Ks[cur][l31 * 128 + ((((kk + 1) * 2 + h) ^ (l31 & 7)) * 8)]);
            st1 = __builtin_amdgcn_mfma_f32_32x32x16_bf16(kf1, qf[kk + 1], st1, 0, 0, 0);
        }
        __builtin_amdgcn_s_setprio(0);

        float p[16];
        #pragma unroll
        for (int r = 0; r < 16; ++r)
            p[r] = __builtin_amdgcn_exp2f(st0[r] + st1[r]);

        {
            float a0 = (p[0] + p[1])   + (p[2] + p[3]);
            float a1 = (p[4] + p[5])   + (p[6] + p[7]);
            float a2 = (p[8] + p[9])   + (p[10] + p[11]);
            float a3 = (p[12] + p[13]) + (p[14] + p[15]);
            lsum += (a0 + a1) + (a2 + a3);
        }

        bf16x8 pf[2];
        #pragma unroll
        for (int half = 0; half < 2; ++half) {
            unsigned a  = cvtpk(p[half*8 + 0], p[half*8 + 1]);
            unsigned bq = cvtpk(p[half*8 + 2], p[half*8 + 3]);
            unsigned c  = cvtpk(p[half*8 + 4], p[half*8 + 5]);
            unsigned d  = cvtpk(p[half*8 + 6], p[half*8 + 7]);
            asm("v_permlane32_swap_b32 %0, %1" : "+v"(a), "+v"(c));
            asm("v_permlane32_swap_b32 %0, %1" : "+v"(bq), "+v"(d));
            uintv4 w = { a, bq, c, d };
            pf[half] = __builtin_bit_cast(bf16x8, w);
        }

        __builtin_amdgcn_s_setprio(1);
        #pragma unroll
        for (int dt = 0; dt < 4; ++dt) {
            int d = dt * 32 + l31;
            bf16x8 vf0 = *reinterpret_cast<const bf16x8*>(
                &Vs[cur][d * KVB + (((0 + h) ^ ((d >> 1) & 3)) * 8)]);
            ctx[dt] = __builtin_amdgcn_mfma_f32_32x32x16_bf16(pf[0], vf0, ctx[dt], 0, 0, 0);
            bf16x8 vf1 = *reinterpret_cast<const bf16x8*>(
                &Vs[cur][d * KVB + (((2 + h) ^ ((d >> 1) & 3)) * 8)]);
            ctx[dt] = __builtin_amdgcn_mfma_f32_32x32x16_bf16(pf[1], vf1, ctx[dt], 0, 0, 0);
        }
        __builtin_amdgcn_s_setprio(0);

        cur = (cur == 2) ? 0 : cur + 1;
        nxt = (nxt == 2) ? 0 : nxt + 1;
    }

    lsum += __shfl_xor(lsum, 32);

    const int qt = qblk * 4 + wv;              // [0,512) 32-row tile
    unsigned short* pp = part + ((size_t)qt * S + split) * (32 * 128);
    #pragma unroll
    for (int rp = 0; rp < 4; ++rp)
        #pragma unroll
        for (int rq = 0; rq < 4; ++rq) {
            const int r = rp * 4 + rq;
            const int q = rq + 8 * rp + 4 * h;
            #pragma unroll
            for (int dt = 0; dt < 4; ++dt)
                pp[q * 128 + dt * 32 + l31] = (unsigned short)(cvtpk(ctx[dt][r], ctx[dt][r]) & 0xFFFFu);
        }
    if (h == 0)
        plsum[((size_t)qt * S + split) * 32 + l31] = lsum;
}

// combine KV-split partials: out = (sum_s part_s) / (sum_s lsum_s)
__global__ __launch_bounds__(256) void reduce_kernel(
    const unsigned short* __restrict__ part,
    const float* __restrict__ plsum,
    float* __restrict__ out, int S)
{
    const int id = blockIdx.x * 256 + threadIdx.x;   // [0, 16384*128/4)
    const int d4 = (id & 31) * 4;
    const int grow = id >> 5;                        // global q row
    const int qt = grow >> 5, q = grow & 31;
    f32x4 c = {0.f, 0.f, 0.f, 0.f};
    float l = 0.f;
    for (int s = 0; s < S; ++s) {
        ushortv4 pv = *reinterpret_cast<const ushortv4*>(
            &part[(((size_t)qt * S + s) * 32 + q) * 128 + d4]);
        #pragma unroll
        for (int j = 0; j < 4; ++j)
            c[j] += __builtin_bit_cast(float, (unsigned)pv[j] << 16);
        l += plsum[((size_t)qt * S + s) * 32 + q];
    }
    float inv = 1.0f / l;
    f32x4 o = { c[0]*inv, c[1]*inv, c[2]*inv, c[3]*inv };
    *reinterpret_cast<f32x4*>(&out[(size_t)grow * 128 + d4]) = o;
}

extern "C" void kernel_launch(void* const* d_in, const int* in_sizes, int n_in,
                              void* d_out, int out_size, void* d_ws, size_t ws_size,
                              hipStream_t stream) {
    const float* x  = (const float*)d_in[0];
    const float* wq = (const float*)d_in[1];
    const float* wk = (const float*)d_in[2];
    const float* wv = (const float*)d_in[3];

    // ws layout: Wb | Qb | Kb | Vt | plsum(max S) | part
    unsigned short* Wb = (unsigned short*)d_ws;                 // 0.79 MB
    unsigned short* Qb = Wb + (size_t)3 * HS * DIMK;
    unsigned short* Kb = Qb + (size_t)ROWS * HS;
    unsigned short* Vt = Kb + (size_t)ROWS * HS;
    float* plsum = (float*)(Vt + (size_t)N_B * HS * N_SEQ);

    const size_t fixed = (size_t)3 * HS * DIMK * 2 + (size_t)3 * ROWS * HS * 2;  // 13.4 MB
    const size_t per_split = (size_t)512 * 32 * 4 + (size_t)512 * 32 * 128 * 2;  // 4.26 MB

    int S;
    if      (ws_size >= fixed + 6 * per_split) S = 6;
    else if (ws_size >= fixed + 4 * per_split) S = 4;
    else if (ws_size >= fixed + 2 * per_split) S = 2;
    else                                       S = 1;

    unsigned short* part = (unsigned short*)(plsum + (size_t)512 * S * 32);

    castw_kernel<<<192, 256, 0, stream>>>(wq, wk, wv, Wb);
    proj_kernel<<<dim3(256, 3), 256, 0, stream>>>(x, Wb, Qb, Kb, Vt);
    attn_kernel<<<dim3(128 * S), 256, 0, stream>>>(Qb, Kb, Vt, part, plsum, S);
    reduce_kernel<<<(ROWS * HS) / 1024, 256, 0, stream>>>(part, plsum, (float*)d_out, S);
}